// Round 10
// baseline (428.024 us; speedup 1.0000x reference)
//
#include <hip/hip_runtime.h>
#include <math.h>

#define BB 8
#define TT 4096
#define DDIM 512
#define KK 4096
#define NN (BB*TT)
#define EPS 0.05f

typedef __attribute__((ext_vector_type(8))) short bf16x8;
typedef __attribute__((ext_vector_type(4))) float f32x4;

__device__ __forceinline__ void async16(void* lds, const void* g) {
  __builtin_amdgcn_global_load_lds((const __attribute__((address_space(1))) void*)g,
                                   (__attribute__((address_space(3))) void*)lds, 16, 0, 0);
}

__device__ __forceinline__ unsigned pk_bf16(float a, float b) {
  unsigned ua = __float_as_uint(a); ua += 0x7FFFu + ((ua >> 16) & 1u);
  unsigned ub = __float_as_uint(b); ub += 0x7FFFu + ((ub >> 16) & 1u);
  return (ua >> 16) | (ub & 0xFFFF0000u);
}

// ---------- prep (embed only): row sum-sq + bf16 (RTNE) conversion ----------
__global__ __launch_bounds__(256) void prep_kernel(const float* __restrict__ src,
                                                   short* __restrict__ dst16,
                                                   float* __restrict__ outv, int mode) {
  int r = blockIdx.x * 4 + (threadIdx.x >> 6);
  int lane = threadIdx.x & 63;
  const float4* row4 = (const float4*)(src + (size_t)r * DDIM);
  float4 v0 = row4[lane];
  float4 v1 = row4[lane + 64];
  uint2 p0, p1;
  p0.x = pk_bf16(v0.x, v0.y); p0.y = pk_bf16(v0.z, v0.w);
  p1.x = pk_bf16(v1.x, v1.y); p1.y = pk_bf16(v1.z, v1.w);
  *(uint2*)(dst16 + (size_t)r * DDIM + lane * 4) = p0;
  *(uint2*)(dst16 + (size_t)r * DDIM + 256 + lane * 4) = p1;
  float ss = v0.x*v0.x + v0.y*v0.y + v0.z*v0.z + v0.w*v0.w
           + v1.x*v1.x + v1.y*v1.y + v1.z*v1.z + v1.w*v1.w;
  #pragma unroll
  for (int off = 32; off; off >>= 1) ss += __shfl_down(ss, off);
  if (lane == 0) outv[r] = mode ? 2.0f / fmaxf(sqrtf(ss), 1e-12f) : ss;
}

// ---------- main MFMA pass: fused x-prep + counted-vmcnt loop (r9, unchanged) ----------
__global__ __launch_bounds__(512, 2) void vq_mfma(const float* __restrict__ xf,
                                                  const short* __restrict__ eb,
                                                  const float* __restrict__ esq,
                                                  float* __restrict__ inv2g,
                                                  float* __restrict__ out_ind,
                                                  int* __restrict__ flags,
                                                  int* __restrict__ list,
                                                  int* __restrict__ cnt) {
  __shared__ __attribute__((aligned(16))) short As[128 * 512];    // 131072 B
  __shared__ __attribute__((aligned(16))) short Bs[2 * 256 * 32]; //  32768 B

  const int tid = threadIdx.x;
  const int lane = tid & 63;
  const int w = tid >> 6;          // 0..7
  const int wr = w >> 2;           // row half (0..1): rows wr*64..+64
  const int wc = w & 3;            // code quarter within 256-tile
  const int q = lane >> 4, c16 = lane & 15;
  const int n0 = blockIdx.x * 128;

  // ---- fused A prep: wave w converts rows w*16 .. w*16+15 ----
  #pragma unroll 2
  for (int j = 0; j < 16; ++j) {
    const int rl = w * 16 + j;       // local row 0..127
    const float4* row4 = (const float4*)(xf + (size_t)(n0 + rl) * DDIM);
    float4 v0 = row4[lane];
    float4 v1 = row4[lane + 64];
    uint2 p0, p1;
    p0.x = pk_bf16(v0.x, v0.y); p0.y = pk_bf16(v0.z, v0.w);
    p1.x = pk_bf16(v1.x, v1.y); p1.y = pk_bf16(v1.z, v1.w);
    // ds_write with chunk swizzle: logical 16B-chunk c stored at c ^ (rl&7).
    const int rx = rl & 7;
    char* rowbase = (char*)(As + rl * 512);
    *(uint2*)(rowbase + ((((lane >> 1)     ) ^ rx) * 16 + (lane & 1) * 8)) = p0;
    *(uint2*)(rowbase + ((((lane >> 1) + 32) ^ rx) * 16 + (lane & 1) * 8)) = p1;
    // identical summation + reduction order as old prep => bit-identical inv2
    float ss = v0.x*v0.x + v0.y*v0.y + v0.z*v0.z + v0.w*v0.w
             + v1.x*v1.x + v1.y*v1.y + v1.z*v1.z + v1.w*v1.w;
    #pragma unroll
    for (int off = 32; off; off >>= 1) ss += __shfl_down(ss, off);
    if (lane == 0) {
      float inv = 2.0f / fmaxf(sqrtf(ss), 1e-12f);
      ((float*)Bs)[rl] = inv;        // park for epilogue (pre-STAGE)
      inv2g[n0 + rl] = inv;          // for cleanup kernel
    }
  }
  __syncthreads();                   // A writes + parked inv2 visible

  f32x4 iv4[4];
  #pragma unroll
  for (int ti = 0; ti < 4; ++ti)
    iv4[ti] = *(const f32x4*)&((const float*)Bs)[wr * 64 + ti * 16 + q * 4];
  __syncthreads();                   // everyone has iv4; Bs reusable

  // ---- B stage thread constants (pair-window swizzle) ----
  const int x = (lane & 7) ^ (lane >> 3);
  const int scode = w * 16 + (lane >> 3) * 2 + (x >> 2);   // k=0 local code
  const short* gB = eb + (size_t)scode * 512 + (x & 3) * 8;

#define STAGE(gn) do {                                                     \
    const short* src_ = gB + (size_t)((gn) >> 4) * (256 * 512) + ((gn) & 15) * 32; \
    short* dst_ = Bs + (((gn) & 1) << 13) + w * 512;                       \
    async16(dst_,        src_);                                            \
    async16(dst_ + 4096, src_ + 128 * 512); } while (0)

  STAGE(0);
  STAGE(1);

  const int sigB8 = ((((c16 & 1) << 2) | q) ^ ((c16 >> 1) & 7)) * 8;
  const int brow0 = (wc * 32 + (c16 >> 1)) * 64 + sigB8;    // + tj*512 + buf*8192
  const int arow0 = (wr * 64 + c16) * 512;                  // + ti*8192 + ach

  float s1[16], s2v[16];
  int   i1[16];
  #pragma unroll
  for (int s = 0; s < 16; ++s) { s1[s] = -3e38f; s2v[s] = -3e38f; i1[s] = 0; }

  asm volatile("s_waitcnt vmcnt(2)" ::: "memory");
  asm volatile("s_barrier" ::: "memory");

  for (int ct = 0; ct < 16; ++ct) {
    float nes[4];
    #pragma unroll
    for (int tj = 0; tj < 4; ++tj)
      nes[tj] = -esq[ct * 256 + wc * 64 + tj * 16 + c16];
    f32x4 acc[4][4];
    #pragma unroll
    for (int ti = 0; ti < 4; ++ti)
      #pragma unroll
      for (int tj = 0; tj < 4; ++tj) acc[ti][tj] = (f32x4){0.f, 0.f, 0.f, 0.f};

    #pragma unroll 2
    for (int s = 0; s < 16; ++s) {
      const int g = ct * 16 + s;
      const short* Ap = As + arow0;
      const short* Bp = Bs + ((g & 1) << 13) + brow0;
      const int ach = ((s * 4 + q) ^ (c16 & 7)) * 8;
      bf16x8 af[4], bf[4];
      #pragma unroll
      for (int ti = 0; ti < 4; ++ti)
        af[ti] = *(const bf16x8*)(Ap + ti * 8192 + ach);
      #pragma unroll
      for (int tj = 0; tj < 4; ++tj)
        bf[tj] = *(const bf16x8*)(Bp + tj * 512);
      __builtin_amdgcn_s_setprio(1);
      #pragma unroll
      for (int ti = 0; ti < 4; ++ti)
        #pragma unroll
        for (int tj = 0; tj < 4; ++tj)
          acc[ti][tj] = __builtin_amdgcn_mfma_f32_16x16x32_bf16(af[ti], bf[tj], acc[ti][tj], 0, 0, 0);
      __builtin_amdgcn_s_setprio(0);
      asm volatile("s_barrier" ::: "memory");   // all waves consumed buf g&1
      if (g <= 253) {
        STAGE(g + 2);
        asm volatile("s_waitcnt vmcnt(2)" ::: "memory");  // STAGE(g+1) landed
      } else if (g == 254) {
        asm volatile("s_waitcnt vmcnt(0)" ::: "memory");
      }
      asm volatile("s_barrier" ::: "memory");   // buf (g+1)&1 readable
    }

    const int colbase = ct * 256 + wc * 64 + c16;
    #pragma unroll
    for (int ti = 0; ti < 4; ++ti)
      #pragma unroll
      for (int r = 0; r < 4; ++r) {
        const int slot = ti * 4 + r;
        const float iv = iv4[ti][r];
        #pragma unroll
        for (int tj = 0; tj < 4; ++tj) {
          float sc = fmaf(acc[ti][tj][r], iv, nes[tj]);
          float mn = fminf(sc, s1[slot]);
          s2v[slot] = fmaxf(s2v[slot], mn);
          if (sc > s1[slot]) { s1[slot] = sc; i1[slot] = colbase + tj * 16; }
        }
      }
  }
#undef STAGE

  __syncthreads();
  float* rS1 = (float*)Bs;           // [4][128]
  float* rS2 = rS1 + 512;
  int*   rI1 = (int*)(rS2 + 512);
  #pragma unroll
  for (int slot = 0; slot < 16; ++slot) {
    float a1 = s1[slot], a2 = s2v[slot]; int ai = i1[slot];
    #pragma unroll
    for (int off = 1; off < 16; off <<= 1) {
      float b1 = __shfl_xor(a1, off);
      float b2 = __shfl_xor(a2, off);
      int   bi = __shfl_xor(ai, off);
      float mn = fminf(a1, b1);
      a2 = fmaxf(fmaxf(a2, b2), mn);
      if (b1 > a1 || (b1 == a1 && bi < ai)) { a1 = b1; ai = bi; }
    }
    if (c16 == 0) {
      int row = wr * 64 + (slot >> 2) * 16 + q * 4 + (slot & 3);
      rS1[wc * 128 + row] = a1; rS2[wc * 128 + row] = a2; rI1[wc * 128 + row] = ai;
    }
  }
  __syncthreads();
  if (tid < 128) {
    float a1 = rS1[tid], a2 = rS2[tid]; int ai = rI1[tid];
    #pragma unroll
    for (int gq = 1; gq < 4; ++gq) {
      float b1 = rS1[gq * 128 + tid], b2 = rS2[gq * 128 + tid]; int bi = rI1[gq * 128 + tid];
      float mn = fminf(a1, b1);
      a2 = fmaxf(fmaxf(a2, b2), mn);
      if (b1 > a1 || (b1 == a1 && bi < ai)) { a1 = b1; ai = bi; }
    }
    const int row = n0 + tid;
    out_ind[row] = (float)ai;
    if (a1 - a2 < EPS) {
      int p = atomicAdd(cnt, 1);
      list[p] = row;
      flags[row] = p + 1;
    } else {
      flags[row] = 0;
    }
  }
}

// ---------- cleanup: exact fp32 rescore of flagged rows ----------
// NEW vs r9: 256-way row parallelism (was 32-way). grid 2048 = 256 row-slots
// x 8 k-chunks; each block handles rows ii = rs, rs+256, ... With n flagged
// rows, per-block iterations drop 8x (n/32 -> n/256); empty blocks exit fast.
__global__ __launch_bounds__(256) void cleanup_kernel(const float* __restrict__ x,
                                                      const float* __restrict__ embed,
                                                      const float* __restrict__ esq,
                                                      const float* __restrict__ inv2,
                                                      const int* __restrict__ list,
                                                      const int* __restrict__ cnt,
                                                      float2* __restrict__ exact) {
  __shared__ float xr[DDIM];
  __shared__ float red_s[4];
  __shared__ int   red_i[4];
  const int rs = blockIdx.x & 255, kc = blockIdx.x >> 8;
  const int tid = threadIdx.x;
  const int lane = tid & 63, wid = tid >> 6;
  const int n = *cnt;
  for (int ii = rs; ii < n; ii += 256) {
    const int row = list[ii];
    __syncthreads();
    if (tid < 128) *(float4*)&xr[tid * 4] = *(const float4*)&x[(size_t)row * DDIM + tid * 4];
    __syncthreads();
    const float iv = inv2[row];
    float bs = -3e38f; int bi = 0;
    for (int cc = 0; cc < 2; ++cc) {
      const int code = kc * 512 + cc * 256 + tid;
      const float4* er = (const float4*)&embed[(size_t)code * DDIM];
      float acc = 0.f;
      for (int d = 0; d < DDIM / 4; ++d) {
        float4 e4 = er[d];
        float4 x4 = *(const float4*)&xr[d * 4];
        acc += x4.x * e4.x + x4.y * e4.y + x4.z * e4.z + x4.w * e4.w;
      }
      float sc = fmaf(acc, iv, -esq[code]);
      if (sc > bs || (sc == bs && code < bi)) { bs = sc; bi = code; }
    }
    #pragma unroll
    for (int off = 1; off < 64; off <<= 1) {
      float b1 = __shfl_xor(bs, off);
      int   b2 = __shfl_xor(bi, off);
      if (b1 > bs || (b1 == bs && b2 < bi)) { bs = b1; bi = b2; }
    }
    if (lane == 0) { red_s[wid] = bs; red_i[wid] = bi; }
    __syncthreads();
    if (tid == 0) {
      for (int ww = 1; ww < 4; ++ww)
        if (red_s[ww] > red_s[0] || (red_s[ww] == red_s[0] && red_i[ww] < red_i[0])) {
          red_s[0] = red_s[ww]; red_i[0] = red_i[ww];
        }
      exact[(size_t)ii * 8 + kc] = make_float2(red_s[0], (float)red_i[0]);
    }
  }
}

// ---------- gather + transpose (merges exact results for flagged rows) ----------
__global__ __launch_bounds__(256) void gather_kernel(const float* __restrict__ embed,
                                                     const int* __restrict__ flags,
                                                     const float2* __restrict__ exact,
                                                     float* __restrict__ out_ind,
                                                     float* __restrict__ out_q) {
  __shared__ int lidx[64];
  __shared__ float trans[64 * 65];
  const int n0 = blockIdx.x * 64;
  const int tid = threadIdx.x;
  if (tid < 64) {
    const int row = n0 + tid;
    const int f = flags[row];
    int idx;
    if (f) {
      float bsv = -3e38f; int bi = 0;
      const float2* e8 = &exact[(size_t)(f - 1) * 8];
      #pragma unroll
      for (int k = 0; k < 8; ++k) {
        float2 t = e8[k];
        int ci = (int)t.y;
        if (t.x > bsv || (t.x == bsv && ci < bi)) { bsv = t.x; bi = ci; }
      }
      idx = bi;
      out_ind[row] = (float)idx;
    } else {
      idx = (int)out_ind[row];
    }
    lidx[tid] = idx;
  }
  __syncthreads();
  const int bb = n0 >> 12;
  const int t0 = n0 & (TT - 1);
  const int w = tid >> 6, lane = tid & 63;
  for (int d0 = 0; d0 < DDIM; d0 += 64) {
    if (d0) __syncthreads();
    #pragma unroll
    for (int qq = 0; qq < 16; ++qq) {
      int tt2 = w * 16 + qq;
      int e = lidx[tt2];
      trans[lane * 65 + tt2] = embed[(size_t)e * DDIM + d0 + lane];
    }
    __syncthreads();
    #pragma unroll
    for (int qq = 0; qq < 4; ++qq) {
      int dl = (tid >> 4) * 4 + qq;
      int t4 = (tid & 15) * 4;
      float4 o;
      o.x = trans[dl * 65 + t4 + 0];
      o.y = trans[dl * 65 + t4 + 1];
      o.z = trans[dl * 65 + t4 + 2];
      o.w = trans[dl * 65 + t4 + 3];
      *(float4*)&out_q[((size_t)bb * DDIM + d0 + dl) * TT + t0 + t4] = o;
    }
  }
}

extern "C" void kernel_launch(void* const* d_in, const int* in_sizes, int n_in,
                              void* d_out, int out_size, void* d_ws, size_t ws_size,
                              hipStream_t stream) {
  const float* x     = (const float*)d_in[0];
  const float* embed = (const float*)d_in[1];
  char* ws = (char*)d_ws;
  short* eb      = (short*)(ws + 33554432);              //  4,194,304 B
  float* esq     = (float*)(ws + 37748736);              //     16,384 B
  float* inv2    = (float*)(ws + 37765120);              //    131,072 B
  int* list      = (int*)(ws + 39993344);                //    131,072 B
  int* flags     = (int*)(ws + 40124416);                //    131,072 B
  float2* exact  = (float2*)(ws + 40255488);             //  2,097,152 B
  int* cnt       = (int*)(ws + 42352640);                //          4 B

  float* out_ind = (float*)d_out;
  float* out_q   = out_ind + NN;

  prep_kernel<<<KK / 4, 256, 0, stream>>>(embed, eb, esq, 0);
  hipMemsetAsync(cnt, 0, 4, stream);
  vq_mfma<<<256, 512, 0, stream>>>(x, eb, esq, inv2, out_ind, flags, list, cnt);
  cleanup_kernel<<<2048, 256, 0, stream>>>(x, embed, esq, inv2, list, cnt, exact);
  gather_kernel<<<NN / 64, 256, 0, stream>>>(embed, flags, exact, out_ind, out_q);
}

// Round 11
// 319.083 us; speedup vs baseline: 1.3414x; 1.3414x over previous
//
#include <hip/hip_runtime.h>
#include <math.h>

#define BB 8
#define TT 4096
#define DDIM 512
#define KK 4096
#define NN (BB*TT)
#define EPS 0.05f

typedef __attribute__((ext_vector_type(8))) short bf16x8;
typedef __attribute__((ext_vector_type(4))) float f32x4;

__device__ __forceinline__ void async16(void* lds, const void* g) {
  __builtin_amdgcn_global_load_lds((const __attribute__((address_space(1))) void*)g,
                                   (__attribute__((address_space(3))) void*)lds, 16, 0, 0);
}

__device__ __forceinline__ unsigned pk_bf16(float a, float b) {
  unsigned ua = __float_as_uint(a); ua += 0x7FFFu + ((ua >> 16) & 1u);
  unsigned ub = __float_as_uint(b); ub += 0x7FFFu + ((ub >> 16) & 1u);
  return (ua >> 16) | (ub & 0xFFFF0000u);
}

// ---------- prep (embed only): row sum-sq + bf16 (RTNE) conversion ----------
__global__ __launch_bounds__(256) void prep_kernel(const float* __restrict__ src,
                                                   short* __restrict__ dst16,
                                                   float* __restrict__ outv, int mode) {
  int r = blockIdx.x * 4 + (threadIdx.x >> 6);
  int lane = threadIdx.x & 63;
  const float4* row4 = (const float4*)(src + (size_t)r * DDIM);
  float4 v0 = row4[lane];
  float4 v1 = row4[lane + 64];
  uint2 p0, p1;
  p0.x = pk_bf16(v0.x, v0.y); p0.y = pk_bf16(v0.z, v0.w);
  p1.x = pk_bf16(v1.x, v1.y); p1.y = pk_bf16(v1.z, v1.w);
  *(uint2*)(dst16 + (size_t)r * DDIM + lane * 4) = p0;
  *(uint2*)(dst16 + (size_t)r * DDIM + 256 + lane * 4) = p1;
  float ss = v0.x*v0.x + v0.y*v0.y + v0.z*v0.z + v0.w*v0.w
           + v1.x*v1.x + v1.y*v1.y + v1.z*v1.z + v1.w*v1.w;
  #pragma unroll
  for (int off = 32; off; off >>= 1) ss += __shfl_down(ss, off);
  if (lane == 0) outv[r] = mode ? 2.0f / fmaxf(sqrtf(ss), 1e-12f) : ss;
}

// ---------- main MFMA pass: fused x-prep + counted-vmcnt loop (r9, unchanged) ----------
__global__ __launch_bounds__(512, 2) void vq_mfma(const float* __restrict__ xf,
                                                  const short* __restrict__ eb,
                                                  const float* __restrict__ esq,
                                                  float* __restrict__ inv2g,
                                                  float* __restrict__ out_ind,
                                                  int* __restrict__ flags,
                                                  int* __restrict__ list,
                                                  int* __restrict__ cnt) {
  __shared__ __attribute__((aligned(16))) short As[128 * 512];    // 131072 B
  __shared__ __attribute__((aligned(16))) short Bs[2 * 256 * 32]; //  32768 B

  const int tid = threadIdx.x;
  const int lane = tid & 63;
  const int w = tid >> 6;          // 0..7
  const int wr = w >> 2;           // row half (0..1): rows wr*64..+64
  const int wc = w & 3;            // code quarter within 256-tile
  const int q = lane >> 4, c16 = lane & 15;
  const int n0 = blockIdx.x * 128;

  // ---- fused A prep: wave w converts rows w*16 .. w*16+15 ----
  #pragma unroll 2
  for (int j = 0; j < 16; ++j) {
    const int rl = w * 16 + j;       // local row 0..127
    const float4* row4 = (const float4*)(xf + (size_t)(n0 + rl) * DDIM);
    float4 v0 = row4[lane];
    float4 v1 = row4[lane + 64];
    uint2 p0, p1;
    p0.x = pk_bf16(v0.x, v0.y); p0.y = pk_bf16(v0.z, v0.w);
    p1.x = pk_bf16(v1.x, v1.y); p1.y = pk_bf16(v1.z, v1.w);
    // ds_write with chunk swizzle: logical 16B-chunk c stored at c ^ (rl&7).
    const int rx = rl & 7;
    char* rowbase = (char*)(As + rl * 512);
    *(uint2*)(rowbase + ((((lane >> 1)     ) ^ rx) * 16 + (lane & 1) * 8)) = p0;
    *(uint2*)(rowbase + ((((lane >> 1) + 32) ^ rx) * 16 + (lane & 1) * 8)) = p1;
    // identical summation + reduction order as old prep => bit-identical inv2
    float ss = v0.x*v0.x + v0.y*v0.y + v0.z*v0.z + v0.w*v0.w
             + v1.x*v1.x + v1.y*v1.y + v1.z*v1.z + v1.w*v1.w;
    #pragma unroll
    for (int off = 32; off; off >>= 1) ss += __shfl_down(ss, off);
    if (lane == 0) {
      float inv = 2.0f / fmaxf(sqrtf(ss), 1e-12f);
      ((float*)Bs)[rl] = inv;        // park for epilogue (pre-STAGE)
      inv2g[n0 + rl] = inv;          // for cleanup kernel
    }
  }
  __syncthreads();                   // A writes + parked inv2 visible

  f32x4 iv4[4];
  #pragma unroll
  for (int ti = 0; ti < 4; ++ti)
    iv4[ti] = *(const f32x4*)&((const float*)Bs)[wr * 64 + ti * 16 + q * 4];
  __syncthreads();                   // everyone has iv4; Bs reusable

  // ---- B stage thread constants (pair-window swizzle) ----
  const int x = (lane & 7) ^ (lane >> 3);
  const int scode = w * 16 + (lane >> 3) * 2 + (x >> 2);   // k=0 local code
  const short* gB = eb + (size_t)scode * 512 + (x & 3) * 8;

#define STAGE(gn) do {                                                     \
    const short* src_ = gB + (size_t)((gn) >> 4) * (256 * 512) + ((gn) & 15) * 32; \
    short* dst_ = Bs + (((gn) & 1) << 13) + w * 512;                       \
    async16(dst_,        src_);                                            \
    async16(dst_ + 4096, src_ + 128 * 512); } while (0)

  STAGE(0);
  STAGE(1);

  const int sigB8 = ((((c16 & 1) << 2) | q) ^ ((c16 >> 1) & 7)) * 8;
  const int brow0 = (wc * 32 + (c16 >> 1)) * 64 + sigB8;    // + tj*512 + buf*8192
  const int arow0 = (wr * 64 + c16) * 512;                  // + ti*8192 + ach

  float s1[16], s2v[16];
  int   i1[16];
  #pragma unroll
  for (int s = 0; s < 16; ++s) { s1[s] = -3e38f; s2v[s] = -3e38f; i1[s] = 0; }

  asm volatile("s_waitcnt vmcnt(2)" ::: "memory");
  asm volatile("s_barrier" ::: "memory");

  for (int ct = 0; ct < 16; ++ct) {
    float nes[4];
    #pragma unroll
    for (int tj = 0; tj < 4; ++tj)
      nes[tj] = -esq[ct * 256 + wc * 64 + tj * 16 + c16];
    f32x4 acc[4][4];
    #pragma unroll
    for (int ti = 0; ti < 4; ++ti)
      #pragma unroll
      for (int tj = 0; tj < 4; ++tj) acc[ti][tj] = (f32x4){0.f, 0.f, 0.f, 0.f};

    #pragma unroll 2
    for (int s = 0; s < 16; ++s) {
      const int g = ct * 16 + s;
      const short* Ap = As + arow0;
      const short* Bp = Bs + ((g & 1) << 13) + brow0;
      const int ach = ((s * 4 + q) ^ (c16 & 7)) * 8;
      bf16x8 af[4], bf[4];
      #pragma unroll
      for (int ti = 0; ti < 4; ++ti)
        af[ti] = *(const bf16x8*)(Ap + ti * 8192 + ach);
      #pragma unroll
      for (int tj = 0; tj < 4; ++tj)
        bf[tj] = *(const bf16x8*)(Bp + tj * 512);
      __builtin_amdgcn_s_setprio(1);
      #pragma unroll
      for (int ti = 0; ti < 4; ++ti)
        #pragma unroll
        for (int tj = 0; tj < 4; ++tj)
          acc[ti][tj] = __builtin_amdgcn_mfma_f32_16x16x32_bf16(af[ti], bf[tj], acc[ti][tj], 0, 0, 0);
      __builtin_amdgcn_s_setprio(0);
      asm volatile("s_barrier" ::: "memory");   // all waves consumed buf g&1
      if (g <= 253) {
        STAGE(g + 2);
        asm volatile("s_waitcnt vmcnt(2)" ::: "memory");  // STAGE(g+1) landed
      } else if (g == 254) {
        asm volatile("s_waitcnt vmcnt(0)" ::: "memory");
      }
      asm volatile("s_barrier" ::: "memory");   // buf (g+1)&1 readable
    }

    const int colbase = ct * 256 + wc * 64 + c16;
    #pragma unroll
    for (int ti = 0; ti < 4; ++ti)
      #pragma unroll
      for (int r = 0; r < 4; ++r) {
        const int slot = ti * 4 + r;
        const float iv = iv4[ti][r];
        #pragma unroll
        for (int tj = 0; tj < 4; ++tj) {
          float sc = fmaf(acc[ti][tj][r], iv, nes[tj]);
          float mn = fminf(sc, s1[slot]);
          s2v[slot] = fmaxf(s2v[slot], mn);
          if (sc > s1[slot]) { s1[slot] = sc; i1[slot] = colbase + tj * 16; }
        }
      }
  }
#undef STAGE

  __syncthreads();
  float* rS1 = (float*)Bs;           // [4][128]
  float* rS2 = rS1 + 512;
  int*   rI1 = (int*)(rS2 + 512);
  #pragma unroll
  for (int slot = 0; slot < 16; ++slot) {
    float a1 = s1[slot], a2 = s2v[slot]; int ai = i1[slot];
    #pragma unroll
    for (int off = 1; off < 16; off <<= 1) {
      float b1 = __shfl_xor(a1, off);
      float b2 = __shfl_xor(a2, off);
      int   bi = __shfl_xor(ai, off);
      float mn = fminf(a1, b1);
      a2 = fmaxf(fmaxf(a2, b2), mn);
      if (b1 > a1 || (b1 == a1 && bi < ai)) { a1 = b1; ai = bi; }
    }
    if (c16 == 0) {
      int row = wr * 64 + (slot >> 2) * 16 + q * 4 + (slot & 3);
      rS1[wc * 128 + row] = a1; rS2[wc * 128 + row] = a2; rI1[wc * 128 + row] = ai;
    }
  }
  __syncthreads();
  if (tid < 128) {
    float a1 = rS1[tid], a2 = rS2[tid]; int ai = rI1[tid];
    #pragma unroll
    for (int gq = 1; gq < 4; ++gq) {
      float b1 = rS1[gq * 128 + tid], b2 = rS2[gq * 128 + tid]; int bi = rI1[gq * 128 + tid];
      float mn = fminf(a1, b1);
      a2 = fmaxf(fmaxf(a2, b2), mn);
      if (b1 > a1 || (b1 == a1 && bi < ai)) { a1 = b1; ai = bi; }
    }
    const int row = n0 + tid;
    out_ind[row] = (float)ai;
    if (a1 - a2 < EPS) {
      int p = atomicAdd(cnt, 1);
      list[p] = row;
      flags[row] = p + 1;
    } else {
      flags[row] = 0;
    }
  }
}

// ---------- cleanup: exact fp32 rescore of flagged rows, 4-row batched ----------
// Grid 256 = 32 row-slots x 8 k-chunks (r10 showed 256 slots thrash L2: same
// bytes, no per-block chunk reuse, +113 us). NEW vs r9: batch FOUR rows per
// codebook-chunk pass -- stage 4 x-rows in LDS (8 KB), stream the 1 MB chunk
// once computing 4 dots/code (LDS x-reads are same-address broadcasts). Cuts
// chunk passes 4x while keeping the reuse pattern that made 32-way fast.
// Per-row arithmetic is the textually identical expression => bit-identical.
__global__ __launch_bounds__(256) void cleanup_kernel(const float* __restrict__ x,
                                                      const float* __restrict__ embed,
                                                      const float* __restrict__ esq,
                                                      const float* __restrict__ inv2,
                                                      const int* __restrict__ list,
                                                      const int* __restrict__ cnt,
                                                      float2* __restrict__ exact) {
  __shared__ float xr[4][DDIM];      // 8 KB
  __shared__ float red_s[4][4];      // [row][wave]
  __shared__ int   red_i[4][4];
  const int rs = blockIdx.x & 31, kc = blockIdx.x >> 5;
  const int tid = threadIdx.x;
  const int lane = tid & 63, wid = tid >> 6;
  const int n = *cnt;
  for (int ii = rs; ii < n; ii += 128) {
    int rows[4];
    #pragma unroll
    for (int b = 0; b < 4; ++b) {
      const int jj = ii + b * 32;
      rows[b] = (jj < n) ? list[jj] : -1;
    }
    __syncthreads();   // previous batch's xr reads done before overwrite
    // stage up to 4 x-rows: 256 threads cover 2 rows per pass (128 float4 each)
    #pragma unroll
    for (int p = 0; p < 2; ++p) {
      const int rb = p * 2 + (tid >> 7);
      const int dd = tid & 127;
      if (rows[rb] >= 0)
        *(float4*)&xr[rb][dd * 4] = *(const float4*)&x[(size_t)rows[rb] * DDIM + dd * 4];
    }
    __syncthreads();
    float iv[4];
    #pragma unroll
    for (int b = 0; b < 4; ++b) iv[b] = (rows[b] >= 0) ? inv2[rows[b]] : 0.f;
    float bs[4]; int bi[4];
    #pragma unroll
    for (int b = 0; b < 4; ++b) { bs[b] = -3e38f; bi[b] = 0; }
    for (int cc = 0; cc < 2; ++cc) {
      const int code = kc * 512 + cc * 256 + tid;
      const float4* er = (const float4*)&embed[(size_t)code * DDIM];
      float a0 = 0.f, a1 = 0.f, a2 = 0.f, a3 = 0.f;
      for (int d = 0; d < DDIM / 4; ++d) {
        float4 e4 = er[d];
        float4 x0 = *(const float4*)&xr[0][d * 4];
        float4 x1 = *(const float4*)&xr[1][d * 4];
        float4 x2 = *(const float4*)&xr[2][d * 4];
        float4 x3 = *(const float4*)&xr[3][d * 4];
        a0 += x0.x * e4.x + x0.y * e4.y + x0.z * e4.z + x0.w * e4.w;
        a1 += x1.x * e4.x + x1.y * e4.y + x1.z * e4.z + x1.w * e4.w;
        a2 += x2.x * e4.x + x2.y * e4.y + x2.z * e4.z + x2.w * e4.w;
        a3 += x3.x * e4.x + x3.y * e4.y + x3.z * e4.z + x3.w * e4.w;
      }
      float sc[4] = { fmaf(a0, iv[0], -esq[code]), fmaf(a1, iv[1], -esq[code]),
                      fmaf(a2, iv[2], -esq[code]), fmaf(a3, iv[3], -esq[code]) };
      #pragma unroll
      for (int b = 0; b < 4; ++b)
        if (sc[b] > bs[b] || (sc[b] == bs[b] && code < bi[b])) { bs[b] = sc[b]; bi[b] = code; }
    }
    #pragma unroll
    for (int b = 0; b < 4; ++b) {
      float v = bs[b]; int vi = bi[b];
      #pragma unroll
      for (int off = 1; off < 64; off <<= 1) {
        float o1 = __shfl_xor(v, off);
        int   o2 = __shfl_xor(vi, off);
        if (o1 > v || (o1 == v && o2 < vi)) { v = o1; vi = o2; }
      }
      if (lane == 0) { red_s[b][wid] = v; red_i[b][wid] = vi; }
    }
    __syncthreads();
    if (tid == 0) {
      #pragma unroll
      for (int b = 0; b < 4; ++b) {
        if (rows[b] < 0) continue;
        float v = red_s[b][0]; int vi = red_i[b][0];
        for (int ww = 1; ww < 4; ++ww)
          if (red_s[b][ww] > v || (red_s[b][ww] == v && red_i[b][ww] < vi)) {
            v = red_s[b][ww]; vi = red_i[b][ww];
          }
        exact[(size_t)(ii + b * 32) * 8 + kc] = make_float2(v, (float)vi);
      }
    }
  }
}

// ---------- gather + transpose (merges exact results for flagged rows) ----------
__global__ __launch_bounds__(256) void gather_kernel(const float* __restrict__ embed,
                                                     const int* __restrict__ flags,
                                                     const float2* __restrict__ exact,
                                                     float* __restrict__ out_ind,
                                                     float* __restrict__ out_q) {
  __shared__ int lidx[64];
  __shared__ float trans[64 * 65];
  const int n0 = blockIdx.x * 64;
  const int tid = threadIdx.x;
  if (tid < 64) {
    const int row = n0 + tid;
    const int f = flags[row];
    int idx;
    if (f) {
      float bsv = -3e38f; int bi = 0;
      const float2* e8 = &exact[(size_t)(f - 1) * 8];
      #pragma unroll
      for (int k = 0; k < 8; ++k) {
        float2 t = e8[k];
        int ci = (int)t.y;
        if (t.x > bsv || (t.x == bsv && ci < bi)) { bsv = t.x; bi = ci; }
      }
      idx = bi;
      out_ind[row] = (float)idx;
    } else {
      idx = (int)out_ind[row];
    }
    lidx[tid] = idx;
  }
  __syncthreads();
  const int bb = n0 >> 12;
  const int t0 = n0 & (TT - 1);
  const int w = tid >> 6, lane = tid & 63;
  for (int d0 = 0; d0 < DDIM; d0 += 64) {
    if (d0) __syncthreads();
    #pragma unroll
    for (int qq = 0; qq < 16; ++qq) {
      int tt2 = w * 16 + qq;
      int e = lidx[tt2];
      trans[lane * 65 + tt2] = embed[(size_t)e * DDIM + d0 + lane];
    }
    __syncthreads();
    #pragma unroll
    for (int qq = 0; qq < 4; ++qq) {
      int dl = (tid >> 4) * 4 + qq;
      int t4 = (tid & 15) * 4;
      float4 o;
      o.x = trans[dl * 65 + t4 + 0];
      o.y = trans[dl * 65 + t4 + 1];
      o.z = trans[dl * 65 + t4 + 2];
      o.w = trans[dl * 65 + t4 + 3];
      *(float4*)&out_q[((size_t)bb * DDIM + d0 + dl) * TT + t0 + t4] = o;
    }
  }
}

extern "C" void kernel_launch(void* const* d_in, const int* in_sizes, int n_in,
                              void* d_out, int out_size, void* d_ws, size_t ws_size,
                              hipStream_t stream) {
  const float* x     = (const float*)d_in[0];
  const float* embed = (const float*)d_in[1];
  char* ws = (char*)d_ws;
  short* eb      = (short*)(ws + 33554432);              //  4,194,304 B
  float* esq     = (float*)(ws + 37748736);              //     16,384 B
  float* inv2    = (float*)(ws + 37765120);              //    131,072 B
  int* list      = (int*)(ws + 39993344);                //    131,072 B
  int* flags     = (int*)(ws + 40124416);                //    131,072 B
  float2* exact  = (float2*)(ws + 40255488);             //  2,097,152 B
  int* cnt       = (int*)(ws + 42352640);                //          4 B

  float* out_ind = (float*)d_out;
  float* out_q   = out_ind + NN;

  prep_kernel<<<KK / 4, 256, 0, stream>>>(embed, eb, esq, 0);
  hipMemsetAsync(cnt, 0, 4, stream);
  vq_mfma<<<256, 512, 0, stream>>>(x, eb, esq, inv2, out_ind, flags, list, cnt);
  cleanup_kernel<<<256, 256, 0, stream>>>(x, embed, esq, inv2, list, cnt, exact);
  gather_kernel<<<NN / 64, 256, 0, stream>>>(embed, flags, exact, out_ind, out_q);
}

// Round 13
// 316.355 us; speedup vs baseline: 1.3530x; 1.0086x over previous
//
#include <hip/hip_runtime.h>
#include <math.h>

#define BB 8
#define TT 4096
#define DDIM 512
#define KK 4096
#define NN (BB*TT)
#define EPS 0.05f

typedef __attribute__((ext_vector_type(8))) short bf16x8;
typedef __attribute__((ext_vector_type(4))) float f32x4;

__device__ __forceinline__ void async16(void* lds, const void* g) {
  __builtin_amdgcn_global_load_lds((const __attribute__((address_space(1))) void*)g,
                                   (__attribute__((address_space(3))) void*)lds, 16, 0, 0);
}

__device__ __forceinline__ unsigned pk_bf16(float a, float b) {
  unsigned ua = __float_as_uint(a); ua += 0x7FFFu + ((ua >> 16) & 1u);
  unsigned ub = __float_as_uint(b); ub += 0x7FFFu + ((ub >> 16) & 1u);
  return (ua >> 16) | (ub & 0xFFFF0000u);
}

// ---------- prep (embed only): row sum-sq + bf16 (RTNE) conversion ----------
__global__ __launch_bounds__(256) void prep_kernel(const float* __restrict__ src,
                                                   short* __restrict__ dst16,
                                                   float* __restrict__ outv, int mode) {
  int r = blockIdx.x * 4 + (threadIdx.x >> 6);
  int lane = threadIdx.x & 63;
  const float4* row4 = (const float4*)(src + (size_t)r * DDIM);
  float4 v0 = row4[lane];
  float4 v1 = row4[lane + 64];
  uint2 p0, p1;
  p0.x = pk_bf16(v0.x, v0.y); p0.y = pk_bf16(v0.z, v0.w);
  p1.x = pk_bf16(v1.x, v1.y); p1.y = pk_bf16(v1.z, v1.w);
  *(uint2*)(dst16 + (size_t)r * DDIM + lane * 4) = p0;
  *(uint2*)(dst16 + (size_t)r * DDIM + 256 + lane * 4) = p1;
  float ss = v0.x*v0.x + v0.y*v0.y + v0.z*v0.z + v0.w*v0.w
           + v1.x*v1.x + v1.y*v1.y + v1.z*v1.z + v1.w*v1.w;
  #pragma unroll
  for (int off = 32; off; off >>= 1) ss += __shfl_down(ss, off);
  if (lane == 0) outv[r] = mode ? 2.0f / fmaxf(sqrtf(ss), 1e-12f) : ss;
}

// ---------- main MFMA pass: fused x-prep + counted-vmcnt loop (r9, unchanged) ----------
__global__ __launch_bounds__(512, 2) void vq_mfma(const float* __restrict__ xf,
                                                  const short* __restrict__ eb,
                                                  const float* __restrict__ esq,
                                                  float* __restrict__ inv2g,
                                                  float* __restrict__ out_ind,
                                                  int* __restrict__ flags,
                                                  int* __restrict__ list,
                                                  int* __restrict__ cnt) {
  __shared__ __attribute__((aligned(16))) short As[128 * 512];    // 131072 B
  __shared__ __attribute__((aligned(16))) short Bs[2 * 256 * 32]; //  32768 B

  const int tid = threadIdx.x;
  const int lane = tid & 63;
  const int w = tid >> 6;          // 0..7
  const int wr = w >> 2;           // row half (0..1): rows wr*64..+64
  const int wc = w & 3;            // code quarter within 256-tile
  const int q = lane >> 4, c16 = lane & 15;
  const int n0 = blockIdx.x * 128;

  // ---- fused A prep: wave w converts rows w*16 .. w*16+15 ----
  #pragma unroll 2
  for (int j = 0; j < 16; ++j) {
    const int rl = w * 16 + j;       // local row 0..127
    const float4* row4 = (const float4*)(xf + (size_t)(n0 + rl) * DDIM);
    float4 v0 = row4[lane];
    float4 v1 = row4[lane + 64];
    uint2 p0, p1;
    p0.x = pk_bf16(v0.x, v0.y); p0.y = pk_bf16(v0.z, v0.w);
    p1.x = pk_bf16(v1.x, v1.y); p1.y = pk_bf16(v1.z, v1.w);
    // ds_write with chunk swizzle: logical 16B-chunk c stored at c ^ (rl&7).
    const int rx = rl & 7;
    char* rowbase = (char*)(As + rl * 512);
    *(uint2*)(rowbase + ((((lane >> 1)     ) ^ rx) * 16 + (lane & 1) * 8)) = p0;
    *(uint2*)(rowbase + ((((lane >> 1) + 32) ^ rx) * 16 + (lane & 1) * 8)) = p1;
    // identical summation + reduction order as old prep => bit-identical inv2
    float ss = v0.x*v0.x + v0.y*v0.y + v0.z*v0.z + v0.w*v0.w
             + v1.x*v1.x + v1.y*v1.y + v1.z*v1.z + v1.w*v1.w;
    #pragma unroll
    for (int off = 32; off; off >>= 1) ss += __shfl_down(ss, off);
    if (lane == 0) {
      float inv = 2.0f / fmaxf(sqrtf(ss), 1e-12f);
      ((float*)Bs)[rl] = inv;        // park for epilogue (pre-STAGE)
      inv2g[n0 + rl] = inv;          // for cleanup kernel
    }
  }
  __syncthreads();                   // A writes + parked inv2 visible

  f32x4 iv4[4];
  #pragma unroll
  for (int ti = 0; ti < 4; ++ti)
    iv4[ti] = *(const f32x4*)&((const float*)Bs)[wr * 64 + ti * 16 + q * 4];
  __syncthreads();                   // everyone has iv4; Bs reusable

  // ---- B stage thread constants (pair-window swizzle) ----
  const int x = (lane & 7) ^ (lane >> 3);
  const int scode = w * 16 + (lane >> 3) * 2 + (x >> 2);   // k=0 local code
  const short* gB = eb + (size_t)scode * 512 + (x & 3) * 8;

#define STAGE(gn) do {                                                     \
    const short* src_ = gB + (size_t)((gn) >> 4) * (256 * 512) + ((gn) & 15) * 32; \
    short* dst_ = Bs + (((gn) & 1) << 13) + w * 512;                       \
    async16(dst_,        src_);                                            \
    async16(dst_ + 4096, src_ + 128 * 512); } while (0)

  STAGE(0);
  STAGE(1);

  const int sigB8 = ((((c16 & 1) << 2) | q) ^ ((c16 >> 1) & 7)) * 8;
  const int brow0 = (wc * 32 + (c16 >> 1)) * 64 + sigB8;    // + tj*512 + buf*8192
  const int arow0 = (wr * 64 + c16) * 512;                  // + ti*8192 + ach

  float s1[16], s2v[16];
  int   i1[16];
  #pragma unroll
  for (int s = 0; s < 16; ++s) { s1[s] = -3e38f; s2v[s] = -3e38f; i1[s] = 0; }

  asm volatile("s_waitcnt vmcnt(2)" ::: "memory");
  asm volatile("s_barrier" ::: "memory");

  for (int ct = 0; ct < 16; ++ct) {
    float nes[4];
    #pragma unroll
    for (int tj = 0; tj < 4; ++tj)
      nes[tj] = -esq[ct * 256 + wc * 64 + tj * 16 + c16];
    f32x4 acc[4][4];
    #pragma unroll
    for (int ti = 0; ti < 4; ++ti)
      #pragma unroll
      for (int tj = 0; tj < 4; ++tj) acc[ti][tj] = (f32x4){0.f, 0.f, 0.f, 0.f};

    #pragma unroll 2
    for (int s = 0; s < 16; ++s) {
      const int g = ct * 16 + s;
      const short* Ap = As + arow0;
      const short* Bp = Bs + ((g & 1) << 13) + brow0;
      const int ach = ((s * 4 + q) ^ (c16 & 7)) * 8;
      bf16x8 af[4], bf[4];
      #pragma unroll
      for (int ti = 0; ti < 4; ++ti)
        af[ti] = *(const bf16x8*)(Ap + ti * 8192 + ach);
      #pragma unroll
      for (int tj = 0; tj < 4; ++tj)
        bf[tj] = *(const bf16x8*)(Bp + tj * 512);
      __builtin_amdgcn_s_setprio(1);
      #pragma unroll
      for (int ti = 0; ti < 4; ++ti)
        #pragma unroll
        for (int tj = 0; tj < 4; ++tj)
          acc[ti][tj] = __builtin_amdgcn_mfma_f32_16x16x32_bf16(af[ti], bf[tj], acc[ti][tj], 0, 0, 0);
      __builtin_amdgcn_s_setprio(0);
      asm volatile("s_barrier" ::: "memory");   // all waves consumed buf g&1
      if (g <= 253) {
        STAGE(g + 2);
        asm volatile("s_waitcnt vmcnt(2)" ::: "memory");  // STAGE(g+1) landed
      } else if (g == 254) {
        asm volatile("s_waitcnt vmcnt(0)" ::: "memory");
      }
      asm volatile("s_barrier" ::: "memory");   // buf (g+1)&1 readable
    }

    const int colbase = ct * 256 + wc * 64 + c16;
    #pragma unroll
    for (int ti = 0; ti < 4; ++ti)
      #pragma unroll
      for (int r = 0; r < 4; ++r) {
        const int slot = ti * 4 + r;
        const float iv = iv4[ti][r];
        #pragma unroll
        for (int tj = 0; tj < 4; ++tj) {
          float sc = fmaf(acc[ti][tj][r], iv, nes[tj]);
          float mn = fminf(sc, s1[slot]);
          s2v[slot] = fmaxf(s2v[slot], mn);
          if (sc > s1[slot]) { s1[slot] = sc; i1[slot] = colbase + tj * 16; }
        }
      }
  }
#undef STAGE

  __syncthreads();
  float* rS1 = (float*)Bs;           // [4][128]
  float* rS2 = rS1 + 512;
  int*   rI1 = (int*)(rS2 + 512);
  #pragma unroll
  for (int slot = 0; slot < 16; ++slot) {
    float a1 = s1[slot], a2 = s2v[slot]; int ai = i1[slot];
    #pragma unroll
    for (int off = 1; off < 16; off <<= 1) {
      float b1 = __shfl_xor(a1, off);
      float b2 = __shfl_xor(a2, off);
      int   bi = __shfl_xor(ai, off);
      float mn = fminf(a1, b1);
      a2 = fmaxf(fmaxf(a2, b2), mn);
      if (b1 > a1 || (b1 == a1 && bi < ai)) { a1 = b1; ai = bi; }
    }
    if (c16 == 0) {
      int row = wr * 64 + (slot >> 2) * 16 + q * 4 + (slot & 3);
      rS1[wc * 128 + row] = a1; rS2[wc * 128 + row] = a2; rI1[wc * 128 + row] = ai;
    }
  }
  __syncthreads();
  if (tid < 128) {
    float a1 = rS1[tid], a2 = rS2[tid]; int ai = rI1[tid];
    #pragma unroll
    for (int gq = 1; gq < 4; ++gq) {
      float b1 = rS1[gq * 128 + tid], b2 = rS2[gq * 128 + tid]; int bi = rI1[gq * 128 + tid];
      float mn = fminf(a1, b1);
      a2 = fmaxf(fmaxf(a2, b2), mn);
      if (b1 > a1 || (b1 == a1 && bi < ai)) { a1 = b1; ai = bi; }
    }
    const int row = n0 + tid;
    out_ind[row] = (float)ai;
    if (a1 - a2 < EPS) {
      int p = atomicAdd(cnt, 1);
      list[p] = row;
      flags[row] = p + 1;
    } else {
      flags[row] = 0;
    }
  }
}

// ---------- cleanup: exact fp32 rescore of flagged rows, 512 threads ----------
// r10/r11 A-B pair: breaking chunk locality costs +113 us (memory), cutting
// passes 4x with locality kept is null => cleanup is VALU-ISSUE-bound at
// 1 wave/SIMD (256 threads). Fix: 512 threads (2 waves/SIMD, 2x FMA issue),
// same 32-slot x 8-chunk grid (locality preserved), 4-row LDS batch kept.
// Each thread owns ONE code of the chunk; per-code arithmetic is the
// textually identical 128-step float4 chain; max-reduce keeps lower-index
// tie-break => bit-identical results.
__global__ __launch_bounds__(512) void cleanup_kernel(const float* __restrict__ x,
                                                      const float* __restrict__ embed,
                                                      const float* __restrict__ esq,
                                                      const float* __restrict__ inv2,
                                                      const int* __restrict__ list,
                                                      const int* __restrict__ cnt,
                                                      float2* __restrict__ exact) {
  __shared__ float xr[4][DDIM];      // 8 KB
  __shared__ float red_s[4][8];      // [row][wave]
  __shared__ int   red_i[4][8];
  const int rs = blockIdx.x & 31, kc = blockIdx.x >> 5;
  const int tid = threadIdx.x;
  const int lane = tid & 63, wid = tid >> 6;
  const int n = *cnt;
  for (int ii = rs; ii < n; ii += 128) {
    int rows[4];
    #pragma unroll
    for (int b = 0; b < 4; ++b) {
      const int jj = ii + b * 32;
      rows[b] = (jj < n) ? list[jj] : -1;
    }
    __syncthreads();   // previous batch's xr/red reads done before overwrite
    // stage up to 4 x-rows: 512 threads cover 4 rows in one pass (128 f4 each)
    {
      const int rb = tid >> 7;
      const int dd = tid & 127;
      if (rows[rb] >= 0)
        *(float4*)&xr[rb][dd * 4] = *(const float4*)&x[(size_t)rows[rb] * DDIM + dd * 4];
    }
    __syncthreads();
    float iv[4];
    #pragma unroll
    for (int b = 0; b < 4; ++b) iv[b] = (rows[b] >= 0) ? inv2[rows[b]] : 0.f;
    const int code = kc * 512 + tid;                  // one code per thread
    const float4* er = (const float4*)&embed[(size_t)code * DDIM];
    float a0 = 0.f, a1 = 0.f, a2 = 0.f, a3 = 0.f;
    for (int d = 0; d < DDIM / 4; ++d) {
      float4 e4 = er[d];
      float4 x0 = *(const float4*)&xr[0][d * 4];
      float4 x1 = *(const float4*)&xr[1][d * 4];
      float4 x2 = *(const float4*)&xr[2][d * 4];
      float4 x3 = *(const float4*)&xr[3][d * 4];
      a0 += x0.x * e4.x + x0.y * e4.y + x0.z * e4.z + x0.w * e4.w;
      a1 += x1.x * e4.x + x1.y * e4.y + x1.z * e4.z + x1.w * e4.w;
      a2 += x2.x * e4.x + x2.y * e4.y + x2.z * e4.z + x2.w * e4.w;
      a3 += x3.x * e4.x + x3.y * e4.y + x3.z * e4.z + x3.w * e4.w;
    }
    const float nesq = -esq[code];
    float sc[4] = { fmaf(a0, iv[0], nesq), fmaf(a1, iv[1], nesq),
                    fmaf(a2, iv[2], nesq), fmaf(a3, iv[3], nesq) };
    #pragma unroll
    for (int b = 0; b < 4; ++b) {
      float v = sc[b]; int vi = code;
      #pragma unroll
      for (int off = 1; off < 64; off <<= 1) {
        float o1 = __shfl_xor(v, off);
        int   o2 = __shfl_xor(vi, off);
        if (o1 > v || (o1 == v && o2 < vi)) { v = o1; vi = o2; }
      }
      if (lane == 0) { red_s[b][wid] = v; red_i[b][wid] = vi; }
    }
    __syncthreads();
    if (tid == 0) {
      #pragma unroll
      for (int b = 0; b < 4; ++b) {
        if (rows[b] < 0) continue;
        float v = red_s[b][0]; int vi = red_i[b][0];
        for (int ww = 1; ww < 8; ++ww)
          if (red_s[b][ww] > v || (red_s[b][ww] == v && red_i[b][ww] < vi)) {
            v = red_s[b][ww]; vi = red_i[b][ww];
          }
        exact[(size_t)(ii + b * 32) * 8 + kc] = make_float2(v, (float)vi);
      }
    }
  }
}

// ---------- gather + transpose (merges exact results for flagged rows) ----------
__global__ __launch_bounds__(256) void gather_kernel(const float* __restrict__ embed,
                                                     const int* __restrict__ flags,
                                                     const float2* __restrict__ exact,
                                                     float* __restrict__ out_ind,
                                                     float* __restrict__ out_q) {
  __shared__ int lidx[64];
  __shared__ float trans[64 * 65];
  const int n0 = blockIdx.x * 64;
  const int tid = threadIdx.x;
  if (tid < 64) {
    const int row = n0 + tid;
    const int f = flags[row];
    int idx;
    if (f) {
      float bsv = -3e38f; int bi = 0;
      const float2* e8 = &exact[(size_t)(f - 1) * 8];
      #pragma unroll
      for (int k = 0; k < 8; ++k) {
        float2 t = e8[k];
        int ci = (int)t.y;
        if (t.x > bsv || (t.x == bsv && ci < bi)) { bsv = t.x; bi = ci; }
      }
      idx = bi;
      out_ind[row] = (float)idx;
    } else {
      idx = (int)out_ind[row];
    }
    lidx[tid] = idx;
  }
  __syncthreads();
  const int bb = n0 >> 12;
  const int t0 = n0 & (TT - 1);
  const int w = tid >> 6, lane = tid & 63;
  for (int d0 = 0; d0 < DDIM; d0 += 64) {
    if (d0) __syncthreads();
    #pragma unroll
    for (int qq = 0; qq < 16; ++qq) {
      int tt2 = w * 16 + qq;
      int e = lidx[tt2];
      trans[lane * 65 + tt2] = embed[(size_t)e * DDIM + d0 + lane];
    }
    __syncthreads();
    #pragma unroll
    for (int qq = 0; qq < 4; ++qq) {
      int dl = (tid >> 4) * 4 + qq;
      int t4 = (tid & 15) * 4;
      float4 o;
      o.x = trans[dl * 65 + t4 + 0];
      o.y = trans[dl * 65 + t4 + 1];
      o.z = trans[dl * 65 + t4 + 2];
      o.w = trans[dl * 65 + t4 + 3];
      *(float4*)&out_q[((size_t)bb * DDIM + d0 + dl) * TT + t0 + t4] = o;
    }
  }
}

extern "C" void kernel_launch(void* const* d_in, const int* in_sizes, int n_in,
                              void* d_out, int out_size, void* d_ws, size_t ws_size,
                              hipStream_t stream) {
  const float* x     = (const float*)d_in[0];
  const float* embed = (const float*)d_in[1];
  char* ws = (char*)d_ws;
  short* eb      = (short*)(ws + 33554432);              //  4,194,304 B
  float* esq     = (float*)(ws + 37748736);              //     16,384 B
  float* inv2    = (float*)(ws + 37765120);              //    131,072 B
  int* list      = (int*)(ws + 39993344);                //    131,072 B
  int* flags     = (int*)(ws + 40124416);                //    131,072 B
  float2* exact  = (float2*)(ws + 40255488);             //  2,097,152 B
  int* cnt       = (int*)(ws + 42352640);                //          4 B

  float* out_ind = (float*)d_out;
  float* out_q   = out_ind + NN;

  prep_kernel<<<KK / 4, 256, 0, stream>>>(embed, eb, esq, 0);
  hipMemsetAsync(cnt, 0, 4, stream);
  vq_mfma<<<256, 512, 0, stream>>>(x, eb, esq, inv2, out_ind, flags, list, cnt);
  cleanup_kernel<<<256, 512, 0, stream>>>(x, embed, esq, inv2, list, cnt, exact);
  gather_kernel<<<NN / 64, 256, 0, stream>>>(embed, flags, exact, out_ind, out_q);
}